// Round 1
// baseline (66.024 us; speedup 1.0000x reference)
//
#include <hip/hip_runtime.h>
#include <math.h>

#define BATCH   8192
#define NI      8
#define NM      3
#define NR      6561   // 3^8
#define NH      81     // 3^4 (inputs 0..3, high digits)
#define NL      81     // 3^4 (inputs 4..7, low digits)
#define NCHUNK  16
#define WPB     4      // waves per block
#define BG      64     // batch elements per block (one per lane)

// partial[chunk][b] = sum over rules in chunk of s[b,r] * (xb[b] . cons[r])
__global__ __launch_bounds__(256) void sugeno_partial(
    const float* __restrict__ x,        // [BATCH][8]
    const float* __restrict__ centers,  // [8][3]
    const float* __restrict__ sigmas,   // [3]
    const float* __restrict__ cons,     // [6561][9]
    float* __restrict__ partial)        // [NCHUNK][BATCH]
{
    __shared__ float pH[NH][BG];
    __shared__ float pL[NL][BG];

    const int lane = threadIdx.x & 63;
    const int wave = threadIdx.x >> 6;
    const int b    = blockIdx.x * BG + lane;

    // load x row (8 f32 = two float4)
    const float4* xv = reinterpret_cast<const float4*>(x + b * NI);
    float4 xa = xv[0], xb4 = xv[1];
    float xr[NI];
    xr[0]=xa.x; xr[1]=xa.y; xr[2]=xa.z; xr[3]=xa.w;
    xr[4]=xb4.x; xr[5]=xb4.y; xr[6]=xb4.z; xr[7]=xb4.w;

    if (wave == 0) {
        float inv[NM];
        #pragma unroll
        for (int m = 0; m < NM; ++m) {
            float s = sigmas[m];
            inv[m] = -0.5f / (s * s);
        }
        float mu[NI][NM];
        #pragma unroll
        for (int j = 0; j < NI; ++j)
            #pragma unroll
            for (int m = 0; m < NM; ++m) {
                float d = xr[j] - centers[j * NM + m];
                mu[j][m] = __expf(d * d * inv[m]);
            }
        // pHigh over inputs 0..3 (rH = m0*27 + m1*9 + m2*3 + m3)
        int idx = 0;
        #pragma unroll
        for (int m0 = 0; m0 < 3; ++m0) { float p0 = mu[0][m0];
            #pragma unroll
            for (int m1 = 0; m1 < 3; ++m1) { float p1 = p0 * mu[1][m1];
                #pragma unroll
                for (int m2 = 0; m2 < 3; ++m2) { float p2 = p1 * mu[2][m2];
                    #pragma unroll
                    for (int m3 = 0; m3 < 3; ++m3) {
                        pH[idx][lane] = p2 * mu[3][m3];
                        ++idx;
                    } } } }
        // pLow over inputs 4..7 (rL = m4*27 + m5*9 + m6*3 + m7)
        idx = 0;
        #pragma unroll
        for (int m4 = 0; m4 < 3; ++m4) { float p4 = mu[4][m4];
            #pragma unroll
            for (int m5 = 0; m5 < 3; ++m5) { float p5 = p4 * mu[5][m5];
                #pragma unroll
                for (int m6 = 0; m6 < 3; ++m6) { float p6 = p5 * mu[6][m6];
                    #pragma unroll
                    for (int m7 = 0; m7 < 3; ++m7) {
                        pL[idx][lane] = p6 * mu[7][m7];
                        ++idx;
                    } } } }
    }
    __syncthreads();

    const int chunk = blockIdx.y * WPB + wave;
    const int rH0 = (chunk * NH) / NCHUNK;
    const int rH1 = ((chunk + 1) * NH) / NCHUNK;

    float acc = 0.0f;
    for (int rH = rH0; rH < rH1; ++rH) {
        const float* crow = cons + (size_t)rH * NL * 9;  // lane-uniform -> s_load
        float U0=0.f,U1=0.f,U2=0.f,U3=0.f,U4=0.f,U5=0.f,U6=0.f,U7=0.f,U8=0.f;
        #pragma unroll 3
        for (int rL = 0; rL < NL; ++rL) {
            float pl = pL[rL][lane];
            U0 += pl * crow[0];
            U1 += pl * crow[1];
            U2 += pl * crow[2];
            U3 += pl * crow[3];
            U4 += pl * crow[4];
            U5 += pl * crow[5];
            U6 += pl * crow[6];
            U7 += pl * crow[7];
            U8 += pl * crow[8];
            crow += 9;
        }
        float dot = U0*xr[0] + U1*xr[1] + U2*xr[2] + U3*xr[3]
                  + U4*xr[4] + U5*xr[5] + U6*xr[6] + U7*xr[7] + U8;
        acc += pH[rH][lane] * dot;
    }
    partial[chunk * BATCH + b] = acc;
}

// out[b] = (sum_chunk partial[chunk][b]) / (prod_j sum_m mu[b,j,m] + 1e-6)
__global__ __launch_bounds__(256) void sugeno_reduce(
    const float* __restrict__ x,
    const float* __restrict__ centers,
    const float* __restrict__ sigmas,
    const float* __restrict__ partial,
    float* __restrict__ out)
{
    const int b = blockIdx.x * blockDim.x + threadIdx.x;
    if (b >= BATCH) return;

    const float4* xv = reinterpret_cast<const float4*>(x + b * NI);
    float4 xa = xv[0], xb4 = xv[1];
    float xr[NI];
    xr[0]=xa.x; xr[1]=xa.y; xr[2]=xa.z; xr[3]=xa.w;
    xr[4]=xb4.x; xr[5]=xb4.y; xr[6]=xb4.z; xr[7]=xb4.w;

    float inv[NM];
    #pragma unroll
    for (int m = 0; m < NM; ++m) {
        float s = sigmas[m];
        inv[m] = -0.5f / (s * s);
    }

    float denom = 1.0f;
    #pragma unroll
    for (int j = 0; j < NI; ++j) {
        float srow = 0.0f;
        #pragma unroll
        for (int m = 0; m < NM; ++m) {
            float d = xr[j] - centers[j * NM + m];
            srow += __expf(d * d * inv[m]);
        }
        denom *= srow;
    }

    float numer = 0.0f;
    #pragma unroll
    for (int k = 0; k < NCHUNK; ++k)
        numer += partial[k * BATCH + b];

    out[b] = numer / (denom + 1e-6f);
}

extern "C" void kernel_launch(void* const* d_in, const int* in_sizes, int n_in,
                              void* d_out, int out_size, void* d_ws, size_t ws_size,
                              hipStream_t stream)
{
    const float* x       = (const float*)d_in[0];
    const float* centers = (const float*)d_in[1];
    const float* sigmas  = (const float*)d_in[2];
    const float* cons    = (const float*)d_in[3];
    float* out           = (float*)d_out;
    float* partial       = (float*)d_ws;   // NCHUNK * BATCH * 4 = 512 KiB

    dim3 grid1(BATCH / BG, NCHUNK / WPB, 1);   // 128 x 4
    sugeno_partial<<<grid1, dim3(256, 1, 1), 0, stream>>>(x, centers, sigmas, cons, partial);

    dim3 grid2(BATCH / 256, 1, 1);
    sugeno_reduce<<<grid2, dim3(256, 1, 1), 0, stream>>>(x, centers, sigmas, partial, out);
}

// Round 2
// 27.871 us; speedup vs baseline: 2.3690x; 2.3690x over previous
//
#include <hip/hip_runtime.h>
#include <math.h>

#define BATCH   8192
#define NI      8
#define NM      3
#define NR      6561   // 3^8
#define NROWS   81     // rH = digits of inputs 0..3
#define NL      81     // rL = digits of inputs 4..7

// select among 3 register-resident floats with a (uniform) runtime index;
// compile-time-constant accesses only -> stays in registers (no scratch)
__device__ __forceinline__ float sel3(const float* a, int i) {
    return (i == 0) ? a[0] : ((i == 1) ? a[1] : a[2]);
}

// partial[chunk][b] = sum over rules with rH in this chunk of s[b,r] * (xb[b] . cons[r])
// chunk index lives ONLY in blockIdx.y -> all cons addressing is provably
// uniform -> scalar (s_load) path, off the VALU critical path.
__global__ __launch_bounds__(256, 8) void sugeno_partial(
    const float* __restrict__ x,        // [BATCH][8]
    const float* __restrict__ centers,  // [8][3]
    const float* __restrict__ sigmas,   // [3]
    const float* __restrict__ cons,     // [6561][9]
    float* __restrict__ partial,        // [nchunk][BATCH]
    int nchunk)
{
    const int b     = blockIdx.x * 256 + threadIdx.x;
    const int chunk = blockIdx.y;

    const float4* xv = reinterpret_cast<const float4*>(x + (size_t)b * NI);
    float4 xa = xv[0], xb4 = xv[1];
    float xr[NI];
    xr[0]=xa.x; xr[1]=xa.y; xr[2]=xa.z; xr[3]=xa.w;
    xr[4]=xb4.x; xr[5]=xb4.y; xr[6]=xb4.z; xr[7]=xb4.w;

    float inv[NM];
    #pragma unroll
    for (int m = 0; m < NM; ++m) {
        float s = sigmas[m];
        inv[m] = -0.5f / (s * s);
    }

    float mu[NI][NM];
    #pragma unroll
    for (int j = 0; j < NI; ++j) {
        #pragma unroll
        for (int m = 0; m < NM; ++m) {
            float d = xr[j] - centers[j * NM + m];
            mu[j][m] = __expf(d * d * inv[m]);
        }
    }

    const int rH0 = (chunk * NROWS) / nchunk;
    const int rH1 = ((chunk + 1) * NROWS) / nchunk;

    // V[i] = sum over rules r in chunk of s[b,r] * cons[r][i]
    float V[9];
    #pragma unroll
    for (int i = 0; i < 9; ++i) V[i] = 0.0f;

    for (int rH = rH0; rH < rH1; ++rH) {
        int d0 = rH / 27, rem = rH - d0 * 27;
        int d1 = rem / 9;  rem -= d1 * 9;
        int d2 = rem / 3;
        int d3 = rem - d2 * 3;
        const float ph = sel3(mu[0], d0) * sel3(mu[1], d1)
                       * sel3(mu[2], d2) * sel3(mu[3], d3);
        const float* __restrict__ crow = cons + (size_t)rH * NL * 9;

        #pragma unroll
        for (int m4 = 0; m4 < 3; ++m4) {
            const float p4 = ph * mu[4][m4];
            #pragma unroll
            for (int m5 = 0; m5 < 3; ++m5) {
                const float p5 = p4 * mu[5][m5];
                #pragma unroll
                for (int m6 = 0; m6 < 3; ++m6) {
                    const float p6 = p5 * mu[6][m6];
                    #pragma unroll
                    for (int m7 = 0; m7 < 3; ++m7) {
                        const float s = p6 * mu[7][m7];
                        const float* cr = crow + (size_t)((((m4*3+m5)*3+m6)*3)+m7) * 9;
                        #pragma unroll
                        for (int i = 0; i < 9; ++i) V[i] += s * cr[i];
                    }
                }
            }
        }
    }

    const float numer = V[0]*xr[0] + V[1]*xr[1] + V[2]*xr[2] + V[3]*xr[3]
                      + V[4]*xr[4] + V[5]*xr[5] + V[6]*xr[6] + V[7]*xr[7]
                      + V[8];
    partial[(size_t)chunk * BATCH + b] = numer;
}

// out[b] = (sum_chunk partial[chunk][b]) / (prod_j sum_m mu[b,j,m] + 1e-6)
__global__ __launch_bounds__(256) void sugeno_reduce(
    const float* __restrict__ x,
    const float* __restrict__ centers,
    const float* __restrict__ sigmas,
    const float* __restrict__ partial,
    float* __restrict__ out,
    int nchunk)
{
    const int b = blockIdx.x * blockDim.x + threadIdx.x;
    if (b >= BATCH) return;

    const float4* xv = reinterpret_cast<const float4*>(x + (size_t)b * NI);
    float4 xa = xv[0], xb4 = xv[1];
    float xr[NI];
    xr[0]=xa.x; xr[1]=xa.y; xr[2]=xa.z; xr[3]=xa.w;
    xr[4]=xb4.x; xr[5]=xb4.y; xr[6]=xb4.z; xr[7]=xb4.w;

    float inv[NM];
    #pragma unroll
    for (int m = 0; m < NM; ++m) {
        float s = sigmas[m];
        inv[m] = -0.5f / (s * s);
    }

    float denom = 1.0f;
    #pragma unroll
    for (int j = 0; j < NI; ++j) {
        float srow = 0.0f;
        #pragma unroll
        for (int m = 0; m < NM; ++m) {
            float d = xr[j] - centers[j * NM + m];
            srow += __expf(d * d * inv[m]);
        }
        denom *= srow;
    }

    float numer = 0.0f;
    #pragma unroll 4
    for (int k = 0; k < nchunk; ++k)
        numer += partial[(size_t)k * BATCH + b];

    out[b] = numer / (denom + 1e-6f);
}

extern "C" void kernel_launch(void* const* d_in, const int* in_sizes, int n_in,
                              void* d_out, int out_size, void* d_ws, size_t ws_size,
                              hipStream_t stream)
{
    const float* x       = (const float*)d_in[0];
    const float* centers = (const float*)d_in[1];
    const float* sigmas  = (const float*)d_in[2];
    const float* cons    = (const float*)d_in[3];
    float* out           = (float*)d_out;
    float* partial       = (float*)d_ws;

    // one chunk per rH row if workspace allows (81*8192*4 = 2.65 MB)
    int nchunk = (int)(ws_size / ((size_t)BATCH * sizeof(float)));
    if (nchunk > NROWS) nchunk = NROWS;
    if (nchunk < 1)     nchunk = 1;

    dim3 grid1(BATCH / 256, nchunk, 1);
    sugeno_partial<<<grid1, dim3(256, 1, 1), 0, stream>>>(x, centers, sigmas, cons,
                                                          partial, nchunk);

    dim3 grid2(BATCH / 256, 1, 1);
    sugeno_reduce<<<grid2, dim3(256, 1, 1), 0, stream>>>(x, centers, sigmas,
                                                         partial, out, nchunk);
}